// Round 1
// baseline (874.747 us; speedup 1.0000x reference)
//
#include <hip/hip_runtime.h>
#include <math.h>

// ArcLoss: x[B,D] fp32, labels[B] int, W[C,D] fp32
// out = [cos_theta (B*C fp32), loss (1 fp32)]
// B=1024, D=512, C=50000 (D hard-assumed; B,C derived)

#define DD 512
#define BM 128
#define BN 128
#define BK 16

// ---------------- Kernel 1: row-normalize x, zero expsum accumulators -----
__global__ __launch_bounds__(256) void arc_normalize(const float* __restrict__ x,
                                                     float* __restrict__ xn,
                                                     float* __restrict__ sumexp,
                                                     int B) {
    int r = blockIdx.x;
    int tid = threadIdx.x;
    const float* xr = x + (size_t)r * DD;
    float v0 = xr[tid];
    float v1 = xr[tid + 256];
    float ss = v0 * v0 + v1 * v1;
    // wave reduce (64-wide)
    #pragma unroll
    for (int off = 32; off > 0; off >>= 1) ss += __shfl_down(ss, off, 64);
    __shared__ float wsum[4];
    int wave = tid >> 6, lane = tid & 63;
    if (lane == 0) wsum[wave] = ss;
    __syncthreads();
    float tot = wsum[0] + wsum[1] + wsum[2] + wsum[3];
    float inv = 1.0f / fmaxf(sqrtf(tot), 1e-12f);
    float* xnr = xn + (size_t)r * DD;
    xnr[tid] = v0 * inv;
    xnr[tid + 256] = v1 * inv;
    if (tid == 0) sumexp[r] = 0.0f;
}

// ---------------- Kernel 2: cos = xn @ W^T, fused exp-sum epilogue --------
__global__ __launch_bounds__(256) void arc_gemm(const float* __restrict__ A,   // xn [B][D]
                                                const float* __restrict__ Wm,  // W  [C][D]
                                                float* __restrict__ out,       // cos [B][C]
                                                float* __restrict__ sumexp,    // [B]
                                                int B, int C) {
    __shared__ float As[BK][BM];
    __shared__ float Bs[BK][BN];

    const int m0 = blockIdx.x * BM;
    const int n0 = blockIdx.y * BN;
    const int tid = threadIdx.x;
    const int tx = tid & 15;   // n direction, 16 threads
    const int ty = tid >> 4;   // m direction, 16 threads

    float acc[8][8];
    #pragma unroll
    for (int i = 0; i < 8; i++)
        #pragma unroll
        for (int j = 0; j < 8; j++) acc[i][j] = 0.0f;

    for (int k0 = 0; k0 < DD; k0 += BK) {
        // Stage A tile (transposed to [k][m]) — 2048 floats, 2 float4/thread
        #pragma unroll
        for (int l = 0; l < 2; l++) {
            int f = tid + l * 256;
            int row = f >> 2, kc = f & 3;
            float4 v = *(const float4*)(A + (size_t)(m0 + row) * DD + k0 + kc * 4);
            As[kc * 4 + 0][row] = v.x;
            As[kc * 4 + 1][row] = v.y;
            As[kc * 4 + 2][row] = v.z;
            As[kc * 4 + 3][row] = v.w;
        }
        // Stage B tile (W rows = classes), bounds-checked on last n-tile
        #pragma unroll
        for (int l = 0; l < 2; l++) {
            int f = tid + l * 256;
            int row = f >> 2, kc = f & 3;
            int n = n0 + row;
            float4 v = make_float4(0.f, 0.f, 0.f, 0.f);
            if (n < C) v = *(const float4*)(Wm + (size_t)n * DD + k0 + kc * 4);
            Bs[kc * 4 + 0][row] = v.x;
            Bs[kc * 4 + 1][row] = v.y;
            Bs[kc * 4 + 2][row] = v.z;
            Bs[kc * 4 + 3][row] = v.w;
        }
        __syncthreads();

        #pragma unroll
        for (int k = 0; k < BK; k++) {
            float4 a0 = *(const float4*)&As[k][ty * 8];
            float4 a1 = *(const float4*)&As[k][ty * 8 + 4];
            float4 b0 = *(const float4*)&Bs[k][tx * 8];
            float4 b1 = *(const float4*)&Bs[k][tx * 8 + 4];
            float a[8] = {a0.x, a0.y, a0.z, a0.w, a1.x, a1.y, a1.z, a1.w};
            float b[8] = {b0.x, b0.y, b0.z, b0.w, b1.x, b1.y, b1.z, b1.w};
            #pragma unroll
            for (int i = 0; i < 8; i++)
                #pragma unroll
                for (int j = 0; j < 8; j++)
                    acc[i][j] = fmaf(a[i], b[j], acc[i][j]);
        }
        __syncthreads();
    }

    // Epilogue: store cos tile + fused sum of exp(S*cos) per row
    const bool full = (n0 + BN <= C);
    #pragma unroll
    for (int i = 0; i < 8; i++) {
        int m = m0 + ty * 8 + i;
        float* orow = out + (size_t)m * C + n0 + tx * 8;
        float s = 0.0f;
        if (full) {
            float4 c0 = make_float4(acc[i][0], acc[i][1], acc[i][2], acc[i][3]);
            float4 c1 = make_float4(acc[i][4], acc[i][5], acc[i][6], acc[i][7]);
            *(float4*)orow = c0;
            *(float4*)(orow + 4) = c1;
            #pragma unroll
            for (int j = 0; j < 8; j++) s += expf(30.0f * acc[i][j]);
        } else {
            #pragma unroll
            for (int j = 0; j < 8; j++) {
                int n = n0 + tx * 8 + j;
                if (n < C) {
                    orow[j] = acc[i][j];
                    s += expf(30.0f * acc[i][j]);
                }
            }
        }
        // reduce across the 16 tx lanes (xor masks stay within 16-lane groups)
        #pragma unroll
        for (int off = 1; off < 16; off <<= 1) s += __shfl_xor(s, off, 64);
        if (tx == 0) atomicAdd(&sumexp[m], s);
    }
}

// ---------------- Kernel 3: per-row loss + mean reduction -----------------
__global__ __launch_bounds__(1024) void arc_finalize(const float* __restrict__ cosm,
                                                     const int* __restrict__ labels,
                                                     const float* __restrict__ sumexp,
                                                     float* __restrict__ out_loss,
                                                     int B, int C) {
    int r = threadIdx.x;
    float loss = 0.0f;
    if (r < B) {
        int lab = labels[r];
        float t_raw = cosm[(size_t)r * C + lab];
        float se = sumexp[r];
        float t = fminf(fmaxf(t_raw, -1.0f + 1e-7f), 1.0f - 1e-7f);
        const float cosM = 0.9210609940028851f;  // cos(0.4)
        const float sinM = 0.3894183423086505f;  // sin(0.4)
        // cos(acos(t) + M) = t*cosM - sqrt(1-t^2)*sinM
        float num = 30.0f * (t * cosM - sqrtf(fmaxf(1.0f - t * t, 0.0f)) * sinM);
        float excl = se - expf(30.0f * t_raw);
        float denom = expf(num) + excl;
        loss = num - logf(denom);
    }
    __shared__ float red[1024];
    red[threadIdx.x] = loss;
    __syncthreads();
    for (int s = 512; s > 0; s >>= 1) {
        if (threadIdx.x < s) red[threadIdx.x] += red[threadIdx.x + s];
        __syncthreads();
    }
    if (threadIdx.x == 0) out_loss[0] = -red[0] / (float)B;
}

extern "C" void kernel_launch(void* const* d_in, const int* in_sizes, int n_in,
                              void* d_out, int out_size, void* d_ws, size_t ws_size,
                              hipStream_t stream) {
    const float* x = (const float*)d_in[0];
    const int* labels = (const int*)d_in[1];
    const float* Wm = (const float*)d_in[2];
    int B = in_sizes[1];              // 1024
    int C = in_sizes[2] / DD;         // 50000
    float* out = (float*)d_out;       // cos_theta [B*C] then loss [1]
    float* xn = (float*)d_ws;                     // B*D floats
    float* sumexp = xn + (size_t)B * DD;          // B floats

    arc_normalize<<<B, 256, 0, stream>>>(x, xn, sumexp, B);
    dim3 grid(B / BM, (C + BN - 1) / BN);
    arc_gemm<<<grid, 256, 0, stream>>>(xn, Wm, out, sumexp, B, C);
    arc_finalize<<<1, 1024, 0, stream>>>(out, labels, sumexp, out + (size_t)B * C, B, C);
}

// Round 2
// 431.070 us; speedup vs baseline: 2.0292x; 2.0292x over previous
//
#include <hip/hip_runtime.h>
#include <hip/hip_bf16.h>
#include <math.h>

// ArcLoss: x[B,D] fp32, labels[B] int, W[C,D] fp32
// out = [cos_theta (B*C fp32), loss (1 fp32)]
// B=1024, D=512, C=50000 (D hard-assumed; B,C derived)

#define DD 512
#define TM 128
#define TN 128
#define TK 32

typedef __attribute__((ext_vector_type(8))) short short8;
typedef __attribute__((ext_vector_type(4))) float f32x4;

// ---------------- Kernel 1: row-normalize x -> bf16, zero expsum ----------
__global__ __launch_bounds__(256) void arc_normalize_bf16(const float* __restrict__ x,
                                                          __hip_bfloat16* __restrict__ xn,
                                                          float* __restrict__ sumexp,
                                                          int B) {
    int r = blockIdx.x;
    int tid = threadIdx.x;
    const float* xr = x + (size_t)r * DD;
    float v0 = xr[tid];
    float v1 = xr[tid + 256];
    float ss = v0 * v0 + v1 * v1;
    #pragma unroll
    for (int off = 32; off > 0; off >>= 1) ss += __shfl_down(ss, off, 64);
    __shared__ float wsum[4];
    if ((tid & 63) == 0) wsum[tid >> 6] = ss;
    __syncthreads();
    float tot = wsum[0] + wsum[1] + wsum[2] + wsum[3];
    float inv = 1.0f / fmaxf(sqrtf(tot), 1e-12f);
    xn[(size_t)r * DD + tid] = __float2bfloat16(v0 * inv);
    xn[(size_t)r * DD + tid + 256] = __float2bfloat16(v1 * inv);
    if (tid == 0) sumexp[r] = 0.0f;
}

// ---------------- Kernel 2: W fp32 -> bf16 --------------------------------
__global__ __launch_bounds__(256) void arc_cvt_w(const float* __restrict__ W,
                                                 __hip_bfloat16* __restrict__ Wb,
                                                 long n) {
    long i = ((long)blockIdx.x * 256 + threadIdx.x) * 8;
    if (i + 8 <= n) {
        float4 a = *(const float4*)(W + i);
        float4 b = *(const float4*)(W + i + 4);
        union { __hip_bfloat16 h[8]; short8 v; } pk;
        pk.h[0] = __float2bfloat16(a.x); pk.h[1] = __float2bfloat16(a.y);
        pk.h[2] = __float2bfloat16(a.z); pk.h[3] = __float2bfloat16(a.w);
        pk.h[4] = __float2bfloat16(b.x); pk.h[5] = __float2bfloat16(b.y);
        pk.h[6] = __float2bfloat16(b.z); pk.h[7] = __float2bfloat16(b.w);
        *(short8*)(Wb + i) = pk.v;
    } else if (i < n) {
        for (long j = i; j < n; j++) Wb[j] = __float2bfloat16(W[j]);
    }
}

// ---------------- Kernel 3: MFMA GEMM cos = xn @ W^T + fused exp-sum ------
__global__ __launch_bounds__(256) void arc_gemm_mfma(const __hip_bfloat16* __restrict__ A,
                                                     const __hip_bfloat16* __restrict__ Wb,
                                                     float* __restrict__ out,
                                                     float* __restrict__ sumexp,
                                                     int C) {
    __shared__ __hip_bfloat16 Als[TM * TK];  // [m][k], 64 B rows, 8 KB
    __shared__ __hip_bfloat16 Bls[TN * TK];  // [n][k], 8 KB

    const int tid = threadIdx.x;
    const int lane = tid & 63;
    const int wave = tid >> 6;
    const int quad = lane >> 4;
    const int l16 = lane & 15;
    const int wm = (wave >> 1) * 64;  // wave's m-offset in tile
    const int wn = (wave & 1) * 64;   // wave's n-offset in tile
    const int m0 = blockIdx.x * TM;
    const int n0 = blockIdx.y * TN;

    f32x4 acc[4][4];
    #pragma unroll
    for (int i = 0; i < 4; i++)
        #pragma unroll
        for (int j = 0; j < 4; j++) acc[i][j] = (f32x4){0.f, 0.f, 0.f, 0.f};

    // Staging: flat chunk f = issue*256 + tid; row = f>>2, kchunk = f&3.
    // LDS byte addr = f*16 == wave_uniform_base + lane*16  (fits global_load_lds)
    const int rowA = tid >> 2, ch = tid & 3;
    const __hip_bfloat16* gA0 = A + (size_t)(m0 + rowA) * DD + ch * 8;
    const __hip_bfloat16* gA1 = gA0 + (size_t)64 * DD;
    int nr0 = n0 + rowA;      if (nr0 >= C) nr0 = C - 1;
    int nr1 = n0 + 64 + rowA; if (nr1 >= C) nr1 = C - 1;
    const __hip_bfloat16* gB0 = Wb + (size_t)nr0 * DD + ch * 8;
    const __hip_bfloat16* gB1 = Wb + (size_t)nr1 * DD + ch * 8;

    char* ldsA0 = (char*)Als + (tid & ~63) * 16;
    char* ldsA1 = ldsA0 + 4096;
    char* ldsB0 = (char*)Bls + (tid & ~63) * 16;
    char* ldsB1 = ldsB0 + 4096;

    for (int k0 = 0; k0 < DD; k0 += TK) {
        __builtin_amdgcn_global_load_lds(
            (const __attribute__((address_space(1))) void*)(gA0 + k0),
            (__attribute__((address_space(3))) void*)ldsA0, 16, 0, 0);
        __builtin_amdgcn_global_load_lds(
            (const __attribute__((address_space(1))) void*)(gA1 + k0),
            (__attribute__((address_space(3))) void*)ldsA1, 16, 0, 0);
        __builtin_amdgcn_global_load_lds(
            (const __attribute__((address_space(1))) void*)(gB0 + k0),
            (__attribute__((address_space(3))) void*)ldsB0, 16, 0, 0);
        __builtin_amdgcn_global_load_lds(
            (const __attribute__((address_space(1))) void*)(gB1 + k0),
            (__attribute__((address_space(3))) void*)ldsB1, 16, 0, 0);
        __syncthreads();  // drains vmcnt: staging visible

        short8 af[4], bfr[4];
        #pragma unroll
        for (int mi = 0; mi < 4; mi++)
            af[mi] = *(const short8*)((const char*)Als + ((wm + mi * 16 + l16) * TK + quad * 8) * 2);
        #pragma unroll
        for (int ni = 0; ni < 4; ni++)
            bfr[ni] = *(const short8*)((const char*)Bls + ((wn + ni * 16 + l16) * TK + quad * 8) * 2);

        #pragma unroll
        for (int mi = 0; mi < 4; mi++)
            #pragma unroll
            for (int ni = 0; ni < 4; ni++)
                acc[mi][ni] = __builtin_amdgcn_mfma_f32_16x16x32_bf16(
                    af[mi], bfr[ni], acc[mi][ni], 0, 0, 0);
        __syncthreads();  // compute done before next staging overwrite
    }

    // Epilogue: D layout row = quad*4+r (m side), col = l16 (n side)
    const bool full = (n0 + TN <= C);
    #pragma unroll
    for (int mi = 0; mi < 4; mi++) {
        float se[4] = {0.f, 0.f, 0.f, 0.f};
        #pragma unroll
        for (int ni = 0; ni < 4; ni++) {
            int n = n0 + wn + ni * 16 + l16;
            f32x4 v = acc[mi][ni];
            if (full || n < C) {
                size_t base = (size_t)(m0 + wm + mi * 16 + quad * 4) * C + n;
                #pragma unroll
                for (int r = 0; r < 4; r++) {
                    out[base + (size_t)r * C] = v[r];
                    se[r] += expf(30.0f * v[r]);
                }
            }
        }
        #pragma unroll
        for (int off = 1; off < 16; off <<= 1) {
            #pragma unroll
            for (int r = 0; r < 4; r++) se[r] += __shfl_xor(se[r], off, 64);
        }
        if (l16 == 0) {
            int mbase = m0 + wm + mi * 16 + quad * 4;
            #pragma unroll
            for (int r = 0; r < 4; r++) atomicAdd(&sumexp[mbase + r], se[r]);
        }
    }
}

// ---------------- fp32 fallback GEMM (round-1, used if ws too small) ------
#define BM 128
#define BN 128
#define BK 16
__global__ __launch_bounds__(256) void arc_normalize_f32(const float* __restrict__ x,
                                                         float* __restrict__ xn,
                                                         float* __restrict__ sumexp,
                                                         int B) {
    int r = blockIdx.x;
    int tid = threadIdx.x;
    const float* xr = x + (size_t)r * DD;
    float v0 = xr[tid];
    float v1 = xr[tid + 256];
    float ss = v0 * v0 + v1 * v1;
    #pragma unroll
    for (int off = 32; off > 0; off >>= 1) ss += __shfl_down(ss, off, 64);
    __shared__ float wsum[4];
    if ((tid & 63) == 0) wsum[tid >> 6] = ss;
    __syncthreads();
    float tot = wsum[0] + wsum[1] + wsum[2] + wsum[3];
    float inv = 1.0f / fmaxf(sqrtf(tot), 1e-12f);
    xn[(size_t)r * DD + tid] = v0 * inv;
    xn[(size_t)r * DD + tid + 256] = v1 * inv;
    if (tid == 0) sumexp[r] = 0.0f;
}

__global__ __launch_bounds__(256) void arc_gemm_f32(const float* __restrict__ A,
                                                    const float* __restrict__ Wm,
                                                    float* __restrict__ out,
                                                    float* __restrict__ sumexp,
                                                    int B, int C) {
    __shared__ float As[BK][BM];
    __shared__ float Bs[BK][BN];
    const int m0 = blockIdx.x * BM;
    const int n0 = blockIdx.y * BN;
    const int tid = threadIdx.x;
    const int tx = tid & 15;
    const int ty = tid >> 4;
    float acc[8][8];
    #pragma unroll
    for (int i = 0; i < 8; i++)
        #pragma unroll
        for (int j = 0; j < 8; j++) acc[i][j] = 0.0f;
    for (int k0 = 0; k0 < DD; k0 += BK) {
        #pragma unroll
        for (int l = 0; l < 2; l++) {
            int f = tid + l * 256;
            int row = f >> 2, kc = f & 3;
            float4 v = *(const float4*)(A + (size_t)(m0 + row) * DD + k0 + kc * 4);
            As[kc * 4 + 0][row] = v.x; As[kc * 4 + 1][row] = v.y;
            As[kc * 4 + 2][row] = v.z; As[kc * 4 + 3][row] = v.w;
        }
        #pragma unroll
        for (int l = 0; l < 2; l++) {
            int f = tid + l * 256;
            int row = f >> 2, kc = f & 3;
            int n = n0 + row;
            float4 v = make_float4(0.f, 0.f, 0.f, 0.f);
            if (n < C) v = *(const float4*)(Wm + (size_t)n * DD + k0 + kc * 4);
            Bs[kc * 4 + 0][row] = v.x; Bs[kc * 4 + 1][row] = v.y;
            Bs[kc * 4 + 2][row] = v.z; Bs[kc * 4 + 3][row] = v.w;
        }
        __syncthreads();
        #pragma unroll
        for (int k = 0; k < BK; k++) {
            float4 a0 = *(const float4*)&As[k][ty * 8];
            float4 a1 = *(const float4*)&As[k][ty * 8 + 4];
            float4 b0 = *(const float4*)&Bs[k][tx * 8];
            float4 b1 = *(const float4*)&Bs[k][tx * 8 + 4];
            float a[8] = {a0.x, a0.y, a0.z, a0.w, a1.x, a1.y, a1.z, a1.w};
            float b[8] = {b0.x, b0.y, b0.z, b0.w, b1.x, b1.y, b1.z, b1.w};
            #pragma unroll
            for (int i = 0; i < 8; i++)
                #pragma unroll
                for (int j = 0; j < 8; j++) acc[i][j] = fmaf(a[i], b[j], acc[i][j]);
        }
        __syncthreads();
    }
    const bool full = (n0 + BN <= C);
    #pragma unroll
    for (int i = 0; i < 8; i++) {
        int m = m0 + ty * 8 + i;
        float* orow = out + (size_t)m * C + n0 + tx * 8;
        float s = 0.0f;
        if (full) {
            *(float4*)orow = make_float4(acc[i][0], acc[i][1], acc[i][2], acc[i][3]);
            *(float4*)(orow + 4) = make_float4(acc[i][4], acc[i][5], acc[i][6], acc[i][7]);
            #pragma unroll
            for (int j = 0; j < 8; j++) s += expf(30.0f * acc[i][j]);
        } else {
            #pragma unroll
            for (int j = 0; j < 8; j++) {
                int n = n0 + tx * 8 + j;
                if (n < C) { orow[j] = acc[i][j]; s += expf(30.0f * acc[i][j]); }
            }
        }
        #pragma unroll
        for (int off = 1; off < 16; off <<= 1) s += __shfl_xor(s, off, 64);
        if (tx == 0) atomicAdd(&sumexp[m], s);
    }
}

// ---------------- Kernel 4: per-row loss + mean ---------------------------
__global__ __launch_bounds__(1024) void arc_finalize(const float* __restrict__ cosm,
                                                     const int* __restrict__ labels,
                                                     const float* __restrict__ sumexp,
                                                     float* __restrict__ out_loss,
                                                     int B, int C) {
    int r = threadIdx.x;
    float loss = 0.0f;
    if (r < B) {
        int lab = labels[r];
        float t_raw = cosm[(size_t)r * C + lab];
        float se = sumexp[r];
        float t = fminf(fmaxf(t_raw, -1.0f + 1e-7f), 1.0f - 1e-7f);
        const float cosM = 0.9210609940028851f;
        const float sinM = 0.3894183423086505f;
        float num = 30.0f * (t * cosM - sqrtf(fmaxf(1.0f - t * t, 0.0f)) * sinM);
        float excl = se - expf(30.0f * t_raw);
        float denom = expf(num) + excl;
        loss = num - logf(denom);
    }
    __shared__ float red[1024];
    red[threadIdx.x] = loss;
    __syncthreads();
    for (int s = 512; s > 0; s >>= 1) {
        if (threadIdx.x < s) red[threadIdx.x] += red[threadIdx.x + s];
        __syncthreads();
    }
    if (threadIdx.x == 0) out_loss[0] = -red[0] / (float)B;
}

extern "C" void kernel_launch(void* const* d_in, const int* in_sizes, int n_in,
                              void* d_out, int out_size, void* d_ws, size_t ws_size,
                              hipStream_t stream) {
    const float* x = (const float*)d_in[0];
    const int* labels = (const int*)d_in[1];
    const float* Wm = (const float*)d_in[2];
    int B = in_sizes[1];
    int C = in_sizes[2] / DD;
    float* out = (float*)d_out;

    size_t need = 4096 + (size_t)B * DD * 2 + (size_t)C * DD * 2 + 256;
    if (ws_size >= need) {
        // bf16 MFMA path
        float* sumexp = (float*)d_ws;                                    // B floats (<=4KB)
        __hip_bfloat16* xnb = (__hip_bfloat16*)((char*)d_ws + 4096);     // B*DD bf16
        __hip_bfloat16* Wb = xnb + (size_t)B * DD;                       // C*DD bf16

        arc_normalize_bf16<<<B, 256, 0, stream>>>(x, xnb, sumexp, B);
        long wn = (long)C * DD;
        long nblk = (wn / 8 + 255) / 256;
        arc_cvt_w<<<(int)nblk, 256, 0, stream>>>(Wm, Wb, wn);
        dim3 grid(B / TM, (C + TN - 1) / TN);
        arc_gemm_mfma<<<grid, 256, 0, stream>>>(xnb, Wb, out, sumexp, C);
        arc_finalize<<<1, 1024, 0, stream>>>(out, labels, sumexp, out + (size_t)B * C, B, C);
    } else {
        // fp32 fallback
        float* xn = (float*)d_ws;
        float* sumexp = xn + (size_t)B * DD;
        arc_normalize_f32<<<B, 256, 0, stream>>>(x, xn, sumexp, B);
        dim3 grid(B / BM, (C + BN - 1) / BN);
        arc_gemm_f32<<<grid, 256, 0, stream>>>(xn, Wm, out, sumexp, B, C);
        arc_finalize<<<1, 1024, 0, stream>>>(out, labels, sumexp, out + (size_t)B * C, B, C);
    }
}